// Round 12
// baseline (123.318 us; speedup 1.0000x reference)
//
#include <hip/hip_runtime.h>
#include <hip/hip_bf16.h>
#include <stdint.h>

#define N_PTS   4096
#define M_CODES 4096
#define ZDIM    1024
// fp8 tiled layout: elem (r,k) at seg(rb)*16384 + kg*128 + r16*8 + ke  (BYTES)
//   rb=r>>4, r16=r&15, kg=k>>3, ke=k&7. Chunk (rb,kg) = 16 rows x 8 k = 128 B.
//   Seg = 16 rows x 1024 k x 1 B = 16 KB.

typedef __attribute__((ext_vector_type(4)))  float f32x4;
typedef __attribute__((ext_vector_type(16))) float f32x16;
typedef __attribute__((ext_vector_type(8)))  int   i32x8;

__device__ __forceinline__ unsigned enc_f32(float f) {
    unsigned u = __float_as_uint(f);
    return (u & 0x80000000u) ? ~u : (u | 0x80000000u);
}
__device__ __forceinline__ float dec_f32(unsigned e) {
    unsigned u = (e & 0x80000000u) ? (e ^ 0x80000000u) : ~e;
    return __uint_as_float(u);
}

// ---------------------------------------------------------------------------
// prep: fp32 -> fp8 e4m3 (OCP) + tiled layout + row sum-of-squares.
// R9 structure (champion): load-all-16-then-process (16 outstanding loads/
// thread), proven shfl reduction, transpose-store via LDS. grid 512.
// (R11 fusion reverted: no done counter.)
// ---------------------------------------------------------------------------
#define PREP_PITCH_B 1040   // bytes per LDS row: 1024 + 16 pad
__global__ __launch_bounds__(256) void prep_kernel(
    const float* __restrict__ z, const float* __restrict__ e,
    uint8_t* __restrict__ zb, uint8_t* __restrict__ eb,
    float* __restrict__ zsq, float* __restrict__ esq,
    unsigned* __restrict__ min_enc) {
    __shared__ uint8_t tile[16 * PREP_PITCH_B];   // ~16.6 KB
    __shared__ float redbuf[16 * 4];

    const int t = threadIdx.x;
    const int b = blockIdx.x;
    if (b < 16) min_enc[b * 256 + t] = 0xFFFFFFFFu;

    const bool is_z = b < 256;
    const int rb = b & 255;
    const float* src = (is_z ? z : e) + (size_t)rb * 16 * ZDIM;
    uint8_t* dst = (is_z ? zb : eb) + (size_t)rb * 16384;   // 16 KB seg
    const int w = t >> 6, lane = t & 63;

    // Phase 0: issue ALL 16 row loads (static indices -> registers).
    float4 v[16];
    #pragma unroll
    for (int it = 0; it < 16; it++)
        v[it] = reinterpret_cast<const float4*>(src + (size_t)it * ZDIM)[t];

    // Phase 1: pack 4 floats -> 4 fp8 into LDS; fp32 row sums.
    #pragma unroll
    for (int it = 0; it < 16; it++) {
        int pk = 0;
        pk = __builtin_amdgcn_cvt_pk_fp8_f32(v[it].x, v[it].y, pk, false);
        pk = __builtin_amdgcn_cvt_pk_fp8_f32(v[it].z, v[it].w, pk, true);
        *reinterpret_cast<int*>(&tile[it * PREP_PITCH_B + t * 4]) = pk;
        float s = v[it].x * v[it].x + v[it].y * v[it].y +
                  v[it].z * v[it].z + v[it].w * v[it].w;
        #pragma unroll
        for (int off = 1; off < 64; off <<= 1) s += __shfl_xor(s, off, 64);
        if (lane == 0) redbuf[it * 4 + w] = s;
    }
    __syncthreads();

    // Phase 2: transpose-store to tiled global (chunk c -> dst + c*8, linear).
    #pragma unroll
    for (int it2 = 0; it2 < 8; it2++) {
        const int c = it2 * 256 + t;          // 0..2047
        const int kg = c >> 4, r16 = c & 15;
        const unsigned long long val = *reinterpret_cast<const unsigned long long*>(
            &tile[r16 * PREP_PITCH_B + kg * 8]);
        *reinterpret_cast<unsigned long long*>(&dst[(size_t)c * 8]) = val;
    }
    if (t < 16) {
        float sq = redbuf[t * 4] + redbuf[t * 4 + 1] +
                   redbuf[t * 4 + 2] + redbuf[t * 4 + 3];
        const int row = rb * 16 + t;
        if (is_z) zsq[row] = sq; else esq[row] = sq;
    }
}

// ---------------------------------------------------------------------------
// gemm_min: R10 champion K-loop BIT-EXACT (32x32x64 MX, 16 stages, A+B via
// triple-buffered global_load_lds, depth-2 DMA, counted `s_waitcnt vmcnt(4)`
// + raw s_barrier boundaries, setprio around MFMA). R11's fused finalize is
// REVERTED (it cost ~16 µs: per-block __threadfence L2 writebacks + a
// serialized last-block tail).
// R12 change: GRID PACKING. R11's direct measurement showed gemm = 44.5 µs
// with OccupancyPercent 19% — 1024 blocks at 3 blocks/CU (768 residency
// slots) = 1.33 rounds + straggler tail. New shape: grid (16,32), each
// block processes TWO adjacent bx tiles sequentially (same by -> zsq_s
// loaded once; A panel L2-hot for tile 1; tile 0's epilogue syncthreads
// fences the As/Bs WAR before tile 1's prologue DMA). 512 blocks <= 768
// slots -> all resident from t=0, no straggler rounds. Only new K-loop
// state is the uniform b_seg0 (SALU) — R8 hard rule respected.
// ---------------------------------------------------------------------------
__global__ __launch_bounds__(256, 4) void gemm_min_kernel(
    const uint8_t* __restrict__ zb, const uint8_t* __restrict__ eb,
    const float* __restrict__ zsq, unsigned* __restrict__ min_enc) {
    __shared__ __align__(16) uint8_t As[3 * 8192];   // 3 bufs x (8 segs x 1 KB)
    __shared__ __align__(16) uint8_t Bs[3 * 8192];   // 3 bufs x (8 segs x 1 KB)
    __shared__ float zsq_s[128];
    __shared__ float colmin[2][128];

    const int t = threadIdx.x;        // 0..255
    const int bx2 = blockIdx.x;       // code (col) block PAIR (0..15)
    const int by = blockIdx.y;        // point (row) block
    const int lane = t & 63;
    const int w = t >> 6;             // 0..3
    const int wm = w >> 1, wn = w & 1;
    const int hi = lane >> 5;         // K-half selector (and C/D row offset)

    if (t < 128) zsq_s[t] = zsq[by * 128 + t];

    const size_t a_seg0 = (size_t)(by * 8) * 16384;

    // Per-lane operand offset within a seg's 1 KB K-stage window:
    // lane l: k = (l>>5)*32 + p*8 + ke -> (l>>5)*512 + p*128 + (l&15)*8;
    // rows 16..31 of the 32-row block live one seg over (seg_sel).
    const int seg_sel = (lane & 31) >> 4;
    const int op_off  = hi * 512 + (lane & 15) * 8;
    const int a_off   = seg_sel * 1024 + op_off;   // also B's in-buf offset

    // A+B staging per stage: 8 A segs + 8 B segs x 1 KB runs (K-window
    // st*1024). 4 instrs x 256 thr x 16 B = 16 KB. Instr j: wave w ->
    // seg j*4+w, for A then B (FIFO order A0,B0,A1,B1 — 4 per stage).
#define DMA_STAGE(st_)                                                        \
    {                                                                         \
        const int buf_ = ((st_) % 3) * 8192;                                  \
        _Pragma("unroll")                                                     \
        for (int j = 0; j < 2; j++) {                                         \
            const int seg_ = j * 4 + w;                                       \
            const uint8_t* ga = zb + a_seg0 + (size_t)seg_ * 16384 +          \
                (st_) * 1024 + lane * 16;                                     \
            __builtin_amdgcn_global_load_lds(                                 \
                (const __attribute__((address_space(1))) void*)ga,            \
                (__attribute__((address_space(3))) void*)(As + buf_ +         \
                    seg_ * 1024 + lane * 16), 16, 0, 0);                      \
            const uint8_t* gb = eb + b_seg0 + (size_t)seg_ * 16384 +          \
                (st_) * 1024 + lane * 16;                                     \
            __builtin_amdgcn_global_load_lds(                                 \
                (const __attribute__((address_space(1))) void*)gb,            \
                (__attribute__((address_space(3))) void*)(Bs + buf_ +         \
                    seg_ * 1024 + lane * 16), 16, 0, 0);                      \
        }                                                                     \
    }

    // Assemble i32x8 fragment from 4x 8B loads (constant-index inserts only;
    // SROA-safe — R1/R2 lesson). Works for LDS pointers (ds_read_b64).
#define LOAD_FRAG(dst_, base_)                                                \
    {                                                                         \
        const int2 d0_ = *(const int2*)((base_));                             \
        const int2 d1_ = *(const int2*)((base_) + 128);                       \
        const int2 d2_ = *(const int2*)((base_) + 256);                       \
        const int2 d3_ = *(const int2*)((base_) + 384);                       \
        dst_[0] = d0_.x; dst_[1] = d0_.y;                                     \
        dst_[2] = d1_.x; dst_[3] = d1_.y;                                     \
        dst_[4] = d2_.x; dst_[5] = d2_.y;                                     \
        dst_[6] = d3_.x; dst_[7] = d3_.y;                                     \
    }

#define MXMFMA(a_, b_, c_)                                                    \
    __builtin_amdgcn_mfma_scale_f32_32x32x64_f8f6f4(                          \
        (a_), (b_), (c_), 0, 0, 0, 0x7F7F7F7F, 0, 0x7F7F7F7F)

    for (int tile = 0; tile < 2; tile++) {
        const int bx = bx2 * 2 + tile;
        const size_t b_seg0 = (size_t)(bx * 8) * 16384;

        f32x16 acc[2][2];
        #pragma unroll
        for (int i = 0; i < 2; i++)
            #pragma unroll
            for (int j = 0; j < 2; j++)
                #pragma unroll
                for (int r = 0; r < 16; r++) acc[i][j][r] = 0.f;

        // Prologue: fill depth-2 pipe; wait DMA(0) only (DMA(1) in flight).
        DMA_STAGE(0);
        DMA_STAGE(1);
        asm volatile("s_waitcnt vmcnt(4)" ::: "memory");
        __builtin_amdgcn_s_barrier();

        #pragma unroll
        for (int st = 0; st < 16; st++) {
            const int buf = (st % 3) * 8192;

            if (st < 14) DMA_STAGE(st + 2);      // depth-2 prefetch

            // B fragments from LDS (wn-keyed; pattern identical to A reads).
            i32x8 bf0, bf1;
            LOAD_FRAG(bf0, Bs + buf + (wn * 4 + 0) * 1024 + a_off);
            LOAD_FRAG(bf1, Bs + buf + (wn * 4 + 2) * 1024 + a_off);

            // Compute stage st: stream A fragments, 2 MX MFMAs each.
            // T5 setprio around the MFMA cluster (0 regs; proven structure).
            __builtin_amdgcn_s_setprio(1);
            #pragma unroll
            for (int am = 0; am < 2; am++) {
                i32x8 af;
                LOAD_FRAG(af, As + buf + (wm * 4 + am * 2) * 1024 + a_off);
                acc[am][0] = MXMFMA(af, bf0, acc[am][0]);
                acc[am][1] = MXMFMA(af, bf1, acc[am][1]);
            }
            __builtin_amdgcn_s_setprio(0);

            // Stage boundary: counted wait (DMA(st+2) stays in flight), raw
            // barrier. st==14: drain DMA(15) fully (no DMA(16) exists).
            if (st < 15) {
                __builtin_amdgcn_sched_barrier(0);
                if (st < 14) {
                    asm volatile("s_waitcnt vmcnt(4)" ::: "memory");
                } else {
                    asm volatile("s_waitcnt vmcnt(0)" ::: "memory");
                }
                __builtin_amdgcn_s_barrier();
                __builtin_amdgcn_sched_barrier(0);
            }
        }

        __syncthreads();   // all LDS reads done; also fences As/Bs WAR

        // Epilogue, 32x32 C/D layout: col = lane&31, row=(r&3)+8*(r>>2)+4*hi.
        #pragma unroll
        for (int an = 0; an < 2; an++) {
            float v = 3.4e38f;
            #pragma unroll
            for (int am = 0; am < 2; am++) {
                const int rbase = wm * 64 + am * 32 + hi * 4;
                f32x16 c = acc[am][an];
                #pragma unroll
                for (int r = 0; r < 16; r++) {
                    const int row = (r & 3) + 8 * (r >> 2);
                    v = fminf(v, zsq_s[rbase + row] - 2.f * c[r]);
                }
            }
            v = fminf(v, __shfl_xor(v, 32, 64));
            if (hi == 0) colmin[wm][wn * 64 + an * 32 + (lane & 31)] = v;
        }
        __syncthreads();
        if (t < 128) {
            const float m = fminf(colmin[0][t], colmin[1][t]);
            atomicMin(&min_enc[bx * 128 + t], enc_f32(m));
        }
        __syncthreads();   // colmin + As/Bs safe before next tile
    }
#undef DMA_STAGE
#undef LOAD_FRAG
#undef MXMFMA
}

// ---------------------------------------------------------------------------
// finalize: mean_j (dec(min_enc[j]) + esq[j]) -> single fp32 scalar.
// R9 structure: uint4/float4 loads, 4 iterations.
// ---------------------------------------------------------------------------
__global__ __launch_bounds__(256) void finalize_kernel(
    const unsigned* __restrict__ min_enc, const float* __restrict__ esq,
    float* __restrict__ out) {
    const int t = threadIdx.x;
    float s = 0.f;
    #pragma unroll
    for (int i = 0; i < M_CODES / (256 * 4); i++) {
        const int j4 = i * 256 + t;
        const uint4  me = reinterpret_cast<const uint4*>(min_enc)[j4];
        const float4 eq = reinterpret_cast<const float4*>(esq)[j4];
        s += (dec_f32(me.x) + eq.x) + (dec_f32(me.y) + eq.y) +
             (dec_f32(me.z) + eq.z) + (dec_f32(me.w) + eq.w);
    }
    #pragma unroll
    for (int off = 1; off < 64; off <<= 1) s += __shfl_xor(s, off, 64);
    __shared__ float red[4];
    if ((t & 63) == 0) red[t >> 6] = s;
    __syncthreads();
    if (t == 0) out[0] = (red[0] + red[1] + red[2] + red[3]) * (1.f / M_CODES);
}

extern "C" void kernel_launch(void* const* d_in, const int* in_sizes, int n_in,
                              void* d_out, int out_size, void* d_ws, size_t ws_size,
                              hipStream_t stream) {
    (void)in_sizes; (void)n_in; (void)out_size; (void)ws_size;
    const float* z = (const float*)d_in[0];
    const float* e = (const float*)d_in[1];
    char* ws = (char*)d_ws;
    uint8_t* zb = (uint8_t*)ws;                                          // 4 MB
    uint8_t* eb = (uint8_t*)(ws + ((size_t)4 << 20));                    // 4 MB
    float* zsq = (float*)(ws + ((size_t)8 << 20));                       // 16 KB
    float* esq = (float*)(ws + ((size_t)8 << 20) + 16384);               // 16 KB
    unsigned* min_enc = (unsigned*)(ws + ((size_t)8 << 20) + 32768);     // 16 KB

    prep_kernel<<<dim3(512), dim3(256), 0, stream>>>(
        z, e, zb, eb, zsq, esq, min_enc);
    gemm_min_kernel<<<dim3(16, 32), dim3(256), 0, stream>>>(
        zb, eb, zsq, min_enc);
    finalize_kernel<<<dim3(1), dim3(256), 0, stream>>>(min_enc, esq, (float*)d_out);
}

// Round 13
// 99.049 us; speedup vs baseline: 1.2450x; 1.2450x over previous
//
#include <hip/hip_runtime.h>
#include <hip/hip_bf16.h>
#include <stdint.h>

#define N_PTS   4096
#define M_CODES 4096
#define ZDIM    1024
// fp8 tiled layout: elem (r,k) at seg(rb)*16384 + kg*128 + r16*8 + ke  (BYTES)
//   rb=r>>4, r16=r&15, kg=k>>3, ke=k&7. Chunk (rb,kg) = 16 rows x 8 k = 128 B.
//   Seg = 16 rows x 1024 k x 1 B = 16 KB.

typedef __attribute__((ext_vector_type(4)))  float f32x4;
typedef __attribute__((ext_vector_type(16))) float f32x16;
typedef __attribute__((ext_vector_type(8)))  int   i32x8;

__device__ __forceinline__ unsigned enc_f32(float f) {
    unsigned u = __float_as_uint(f);
    return (u & 0x80000000u) ? ~u : (u | 0x80000000u);
}
__device__ __forceinline__ float dec_f32(unsigned e) {
    unsigned u = (e & 0x80000000u) ? (e ^ 0x80000000u) : ~e;
    return __uint_as_float(u);
}

// ---------------------------------------------------------------------------
// prep: fp32 -> fp8 e4m3 (OCP) + tiled layout + row sum-of-squares.
// R9 structure (champion): load-all-16-then-process (16 outstanding loads/
// thread), proven shfl reduction, transpose-store via LDS. grid 512.
// ---------------------------------------------------------------------------
#define PREP_PITCH_B 1040   // bytes per LDS row: 1024 + 16 pad
__global__ __launch_bounds__(256) void prep_kernel(
    const float* __restrict__ z, const float* __restrict__ e,
    uint8_t* __restrict__ zb, uint8_t* __restrict__ eb,
    float* __restrict__ zsq, float* __restrict__ esq,
    unsigned* __restrict__ min_enc) {
    __shared__ uint8_t tile[16 * PREP_PITCH_B];   // ~16.6 KB
    __shared__ float redbuf[16 * 4];

    const int t = threadIdx.x;
    const int b = blockIdx.x;
    if (b < 16) min_enc[b * 256 + t] = 0xFFFFFFFFu;

    const bool is_z = b < 256;
    const int rb = b & 255;
    const float* src = (is_z ? z : e) + (size_t)rb * 16 * ZDIM;
    uint8_t* dst = (is_z ? zb : eb) + (size_t)rb * 16384;   // 16 KB seg
    const int w = t >> 6, lane = t & 63;

    // Phase 0: issue ALL 16 row loads (static indices -> registers).
    float4 v[16];
    #pragma unroll
    for (int it = 0; it < 16; it++)
        v[it] = reinterpret_cast<const float4*>(src + (size_t)it * ZDIM)[t];

    // Phase 1: pack 4 floats -> 4 fp8 into LDS; fp32 row sums.
    #pragma unroll
    for (int it = 0; it < 16; it++) {
        int pk = 0;
        pk = __builtin_amdgcn_cvt_pk_fp8_f32(v[it].x, v[it].y, pk, false);
        pk = __builtin_amdgcn_cvt_pk_fp8_f32(v[it].z, v[it].w, pk, true);
        *reinterpret_cast<int*>(&tile[it * PREP_PITCH_B + t * 4]) = pk;
        float s = v[it].x * v[it].x + v[it].y * v[it].y +
                  v[it].z * v[it].z + v[it].w * v[it].w;
        #pragma unroll
        for (int off = 1; off < 64; off <<= 1) s += __shfl_xor(s, off, 64);
        if (lane == 0) redbuf[it * 4 + w] = s;
    }
    __syncthreads();

    // Phase 2: transpose-store to tiled global (chunk c -> dst + c*8, linear).
    #pragma unroll
    for (int it2 = 0; it2 < 8; it2++) {
        const int c = it2 * 256 + t;          // 0..2047
        const int kg = c >> 4, r16 = c & 15;
        const unsigned long long val = *reinterpret_cast<const unsigned long long*>(
            &tile[r16 * PREP_PITCH_B + kg * 8]);
        *reinterpret_cast<unsigned long long*>(&dst[(size_t)c * 8]) = val;
    }
    if (t < 16) {
        float sq = redbuf[t * 4] + redbuf[t * 4 + 1] +
                   redbuf[t * 4 + 2] + redbuf[t * 4 + 3];
        const int row = rb * 16 + t;
        if (is_z) zsq[row] = sq; else esq[row] = sq;
    }
}

// ---------------------------------------------------------------------------
// gemm_min: R10 CHAMPION, restored bit-exact (102.1 µs total). 32x32x64 MX
// (unit e8m0 scales = exact e4m3 math), 16 stages, A+B staged via
// triple-buffered global_load_lds, depth-2 DMA prefetch, counted
// `s_waitcnt vmcnt(4)` + raw s_barrier boundaries, T5 setprio around MFMA.
// Grid (32,32), one tile per block (R12's two-tile loop quadrupled
// VGPR_Count to 256 and regressed; reverted).
// Session ledger for future reference: structural levers tested on this
// kernel — MX rate swap (+3 µs), counted-vmcnt pipeline (+6.4 µs, R5),
// B-dedup via LDS (+1 µs), setprio (+0.5 µs), reg-dbuf B (spill, R8),
// launch fusion (−16 µs, R11), grid packing (−21 µs, R12). Remaining
// non-MFMA gemm time is LDS/latency-structure-bound; harness fills
// (~45 µs) dominate the fixed term.
// ---------------------------------------------------------------------------
__global__ __launch_bounds__(256, 4) void gemm_min_kernel(
    const uint8_t* __restrict__ zb, const uint8_t* __restrict__ eb,
    const float* __restrict__ zsq, unsigned* __restrict__ min_enc) {
    __shared__ __align__(16) uint8_t As[3 * 8192];   // 3 bufs x (8 segs x 1 KB)
    __shared__ __align__(16) uint8_t Bs[3 * 8192];   // 3 bufs x (8 segs x 1 KB)
    __shared__ float zsq_s[128];
    __shared__ float colmin[2][128];

    const int t = threadIdx.x;        // 0..255
    const int bx = blockIdx.x;        // code (col) block
    const int by = blockIdx.y;        // point (row) block
    const int lane = t & 63;
    const int w = t >> 6;             // 0..3
    const int wm = w >> 1, wn = w & 1;
    const int hi = lane >> 5;         // K-half selector (and C/D row offset)

    if (t < 128) zsq_s[t] = zsq[by * 128 + t];

    f32x16 acc[2][2];
    #pragma unroll
    for (int i = 0; i < 2; i++)
        #pragma unroll
        for (int j = 0; j < 2; j++)
            #pragma unroll
            for (int r = 0; r < 16; r++) acc[i][j][r] = 0.f;

    const size_t a_seg0 = (size_t)(by * 8) * 16384;
    const size_t b_seg0 = (size_t)(bx * 8) * 16384;

    // Per-lane operand offset within a seg's 1 KB K-stage window:
    // lane l: k = (l>>5)*32 + p*8 + ke -> (l>>5)*512 + p*128 + (l&15)*8;
    // rows 16..31 of the 32-row block live one seg over (seg_sel).
    const int seg_sel = (lane & 31) >> 4;
    const int op_off  = hi * 512 + (lane & 15) * 8;
    const int a_off   = seg_sel * 1024 + op_off;   // also B's in-buf offset

    // A+B staging per stage: 8 A segs + 8 B segs x 1 KB runs (K-window
    // st*1024). 4 instrs x 256 thr x 16 B = 16 KB. Instr j: wave w ->
    // seg j*4+w, for A then B (FIFO order A0,B0,A1,B1 — 4 per stage).
#define DMA_STAGE(st_)                                                        \
    {                                                                         \
        const int buf_ = ((st_) % 3) * 8192;                                  \
        _Pragma("unroll")                                                     \
        for (int j = 0; j < 2; j++) {                                         \
            const int seg_ = j * 4 + w;                                       \
            const uint8_t* ga = zb + a_seg0 + (size_t)seg_ * 16384 +          \
                (st_) * 1024 + lane * 16;                                     \
            __builtin_amdgcn_global_load_lds(                                 \
                (const __attribute__((address_space(1))) void*)ga,            \
                (__attribute__((address_space(3))) void*)(As + buf_ +         \
                    seg_ * 1024 + lane * 16), 16, 0, 0);                      \
            const uint8_t* gb = eb + b_seg0 + (size_t)seg_ * 16384 +          \
                (st_) * 1024 + lane * 16;                                     \
            __builtin_amdgcn_global_load_lds(                                 \
                (const __attribute__((address_space(1))) void*)gb,            \
                (__attribute__((address_space(3))) void*)(Bs + buf_ +         \
                    seg_ * 1024 + lane * 16), 16, 0, 0);                      \
        }                                                                     \
    }

    // Assemble i32x8 fragment from 4x 8B loads (constant-index inserts only;
    // SROA-safe — R1/R2 lesson). Works for LDS pointers (ds_read_b64).
#define LOAD_FRAG(dst_, base_)                                                \
    {                                                                         \
        const int2 d0_ = *(const int2*)((base_));                             \
        const int2 d1_ = *(const int2*)((base_) + 128);                       \
        const int2 d2_ = *(const int2*)((base_) + 256);                       \
        const int2 d3_ = *(const int2*)((base_) + 384);                       \
        dst_[0] = d0_.x; dst_[1] = d0_.y;                                     \
        dst_[2] = d1_.x; dst_[3] = d1_.y;                                     \
        dst_[4] = d2_.x; dst_[5] = d2_.y;                                     \
        dst_[6] = d3_.x; dst_[7] = d3_.y;                                     \
    }

#define MXMFMA(a_, b_, c_)                                                    \
    __builtin_amdgcn_mfma_scale_f32_32x32x64_f8f6f4(                          \
        (a_), (b_), (c_), 0, 0, 0, 0x7F7F7F7F, 0, 0x7F7F7F7F)

    // Prologue: fill depth-2 pipe; wait DMA(0) only (DMA(1) stays in flight).
    DMA_STAGE(0);
    DMA_STAGE(1);
    asm volatile("s_waitcnt vmcnt(4)" ::: "memory");
    __builtin_amdgcn_s_barrier();

    #pragma unroll
    for (int st = 0; st < 16; st++) {
        const int buf = (st % 3) * 8192;

        if (st < 14) DMA_STAGE(st + 2);      // depth-2 prefetch

        // B fragments from LDS (wn-keyed; pattern identical to A reads).
        i32x8 bf0, bf1;
        LOAD_FRAG(bf0, Bs + buf + (wn * 4 + 0) * 1024 + a_off);
        LOAD_FRAG(bf1, Bs + buf + (wn * 4 + 2) * 1024 + a_off);

        // Compute stage st: stream A fragments, 2 MX MFMAs each.
        // T5 setprio around the MFMA cluster (0 regs; proven structure).
        __builtin_amdgcn_s_setprio(1);
        #pragma unroll
        for (int am = 0; am < 2; am++) {
            i32x8 af;
            LOAD_FRAG(af, As + buf + (wm * 4 + am * 2) * 1024 + a_off);
            acc[am][0] = MXMFMA(af, bf0, acc[am][0]);
            acc[am][1] = MXMFMA(af, bf1, acc[am][1]);
        }
        __builtin_amdgcn_s_setprio(0);

        // Stage boundary: counted wait (DMA(st+2) stays in flight), raw
        // barrier. st==14: drain DMA(15) fully (no DMA(16) exists).
        if (st < 15) {
            __builtin_amdgcn_sched_barrier(0);
            if (st < 14) {
                asm volatile("s_waitcnt vmcnt(4)" ::: "memory");
            } else {
                asm volatile("s_waitcnt vmcnt(0)" ::: "memory");
            }
            __builtin_amdgcn_s_barrier();
            __builtin_amdgcn_sched_barrier(0);
        }
    }
#undef DMA_STAGE
#undef LOAD_FRAG
#undef MXMFMA

    __syncthreads();

    // Epilogue, 32x32 C/D layout: col = lane&31, row = (r&3)+8*(r>>2)+4*hi.
    #pragma unroll
    for (int an = 0; an < 2; an++) {
        float v = 3.4e38f;
        #pragma unroll
        for (int am = 0; am < 2; am++) {
            const int rbase = wm * 64 + am * 32 + hi * 4;
            f32x16 c = acc[am][an];
            #pragma unroll
            for (int r = 0; r < 16; r++) {
                const int row = (r & 3) + 8 * (r >> 2);
                v = fminf(v, zsq_s[rbase + row] - 2.f * c[r]);
            }
        }
        v = fminf(v, __shfl_xor(v, 32, 64));
        if (hi == 0) colmin[wm][wn * 64 + an * 32 + (lane & 31)] = v;
    }
    __syncthreads();
    if (t < 128) {
        const float m = fminf(colmin[0][t], colmin[1][t]);
        atomicMin(&min_enc[bx * 128 + t], enc_f32(m));
    }
}

// ---------------------------------------------------------------------------
// finalize: mean_j (dec(min_enc[j]) + esq[j]) -> single fp32 scalar.
// R9 structure: uint4/float4 loads, 4 iterations.
// ---------------------------------------------------------------------------
__global__ __launch_bounds__(256) void finalize_kernel(
    const unsigned* __restrict__ min_enc, const float* __restrict__ esq,
    float* __restrict__ out) {
    const int t = threadIdx.x;
    float s = 0.f;
    #pragma unroll
    for (int i = 0; i < M_CODES / (256 * 4); i++) {
        const int j4 = i * 256 + t;
        const uint4  me = reinterpret_cast<const uint4*>(min_enc)[j4];
        const float4 eq = reinterpret_cast<const float4*>(esq)[j4];
        s += (dec_f32(me.x) + eq.x) + (dec_f32(me.y) + eq.y) +
             (dec_f32(me.z) + eq.z) + (dec_f32(me.w) + eq.w);
    }
    #pragma unroll
    for (int off = 1; off < 64; off <<= 1) s += __shfl_xor(s, off, 64);
    __shared__ float red[4];
    if ((t & 63) == 0) red[t >> 6] = s;
    __syncthreads();
    if (t == 0) out[0] = (red[0] + red[1] + red[2] + red[3]) * (1.f / M_CODES);
}

extern "C" void kernel_launch(void* const* d_in, const int* in_sizes, int n_in,
                              void* d_out, int out_size, void* d_ws, size_t ws_size,
                              hipStream_t stream) {
    (void)in_sizes; (void)n_in; (void)out_size; (void)ws_size;
    const float* z = (const float*)d_in[0];
    const float* e = (const float*)d_in[1];
    char* ws = (char*)d_ws;
    uint8_t* zb = (uint8_t*)ws;                                          // 4 MB
    uint8_t* eb = (uint8_t*)(ws + ((size_t)4 << 20));                    // 4 MB
    float* zsq = (float*)(ws + ((size_t)8 << 20));                       // 16 KB
    float* esq = (float*)(ws + ((size_t)8 << 20) + 16384);               // 16 KB
    unsigned* min_enc = (unsigned*)(ws + ((size_t)8 << 20) + 32768);     // 16 KB

    prep_kernel<<<dim3(512), dim3(256), 0, stream>>>(
        z, e, zb, eb, zsq, esq, min_enc);
    gemm_min_kernel<<<dim3(32, 32), dim3(256), 0, stream>>>(
        zb, eb, zsq, min_enc);
    finalize_kernel<<<dim3(1), dim3(256), 0, stream>>>(min_enc, esq, (float*)d_out);
}